// Round 5
// baseline (155.585 us; speedup 1.0000x reference)
//
#include <hip/hip_runtime.h>
#include <hip/hip_bf16.h>
#include <math.h>

typedef unsigned short u16;
typedef unsigned int u32;
typedef __attribute__((ext_vector_type(8))) short short8;
typedef __attribute__((ext_vector_type(4))) float floatx4;

// Problem constants
constexpr int kB     = 8;
constexpr int kSEQ   = 256;
constexpr int kMEM   = 768;
constexpr int kTOTAL = 1024;  // MEM+SEQ

__device__ __forceinline__ float bf2f(u16 u) {
  return __uint_as_float(((u32)u) << 16);
}
__device__ __forceinline__ u16 f2bf(float f) {
  __hip_bfloat16 h = __float2bfloat16(f);
  return *reinterpret_cast<u16*>(&h);
}
__device__ __forceinline__ void gload_lds16(const u16* g, u16* l) {
  __builtin_amdgcn_global_load_lds(
      (__attribute__((address_space(1))) const unsigned int*)g,
      (__attribute__((address_space(3))) unsigned int*)l, 16, 0, 0);
}

// ---------------------------------------------------------------------------
// Fused prep (one kernel, disjoint block ranges):
//   blocks [0,1024):    Rrel_bf[s,:] = bf16(PE(s)@W_rel);
//                       vR'[h,s] = 0.125*(v·R_f32 - u·R_bf16)
//   blocks [1024,3072): xcat -> bf16
//   blocks [3072,3264): W_qkv^T -> bf16
//   blocks [3264,3328): W_out^T -> bf16
// ---------------------------------------------------------------------------
__device__ __forceinline__ void wtconv_body(
    const float* __restrict__ W, u16* __restrict__ Wt, int K, int N,
    int n0, int k0, int tid, float (*tile)[65])
{
  int r = tid >> 4, c4 = (tid & 15) * 4;
#pragma unroll
  for (int v = 0; v < 4; v++) {
    float4 w4 = *(const float4*)(W + (size_t)(k0 + v * 16 + r) * N + n0 + c4);
    tile[v * 16 + r][c4 + 0] = w4.x;
    tile[v * 16 + r][c4 + 1] = w4.y;
    tile[v * 16 + r][c4 + 2] = w4.z;
    tile[v * 16 + r][c4 + 3] = w4.w;
  }
  __syncthreads();
#pragma unroll
  for (int v = 0; v < 4; v++) {
    int rn = v * 16 + r;
    ushort4 o;
    o.x = f2bf(tile[c4 + 0][rn]);
    o.y = f2bf(tile[c4 + 1][rn]);
    o.z = f2bf(tile[c4 + 2][rn]);
    o.w = f2bf(tile[c4 + 3][rn]);
    *(ushort4*)(Wt + (size_t)(n0 + rn) * K + k0 + c4) = o;
  }
}

__global__ __launch_bounds__(256) void prep_kernel(
    const float* __restrict__ x, const float* __restrict__ memf,
    const float* __restrict__ W_qkv, const float* __restrict__ W_out,
    const float* __restrict__ W_rel, const float* __restrict__ v_emb,
    const float* __restrict__ u_emb,
    u16* __restrict__ Xb, u16* __restrict__ WqkvT, u16* __restrict__ WoutT,
    u16* __restrict__ Rrel_bf, float* __restrict__ vR)
{
  __shared__ float tile[64][65];
  __shared__ float pe[22];
  __shared__ float prod[512];
  int bid = blockIdx.x;
  int t = threadIdx.x;
  if (bid < 1024) {
    int s = bid;
    if (t < 22) {
      int o = (t < 11) ? t : (t - 11);
      float mult = ldexpf(3.14159265358979323846f, o - 10);  // 2^(o-10) * pi
      float ang = (float)s * mult;
      pe[t] = (t < 11) ? sinf(ang) : cosf(ang);
    }
    __syncthreads();
#pragma unroll
    for (int c = 0; c < 2; c++) {
      int j = t + c * 256;
      float acc = 0.f;
#pragma unroll
      for (int o = 0; o < 22; ++o) acc += pe[o] * W_rel[o * 512 + j];
      u16 rbf = f2bf(acc);
      Rrel_bf[(size_t)s * 512 + j] = rbf;
      prod[j] = acc * v_emb[j & 63] - bf2f(rbf) * u_emb[j & 63];
    }
    __syncthreads();
    if (t < 8) {
      float a = 0.f;
#pragma unroll 8
      for (int d = 0; d < 64; d++) a += prod[t * 64 + d];
      vR[t * 1024 + s] = a * 0.125f;   // prescaled
    }
  } else if (bid < 3072) {
    int idx = (bid - 1024) * 256 + t;        // 8 elems each
    int row = idx >> 6, c8 = idx & 63;
    int b = row >> 10, pos = row & 1023;
    const float* src = (pos < kMEM)
        ? memf + (size_t)(b * kMEM + pos) * 512
        : x    + (size_t)(b * kSEQ + pos - kMEM) * 512;
    const float4* s4 = (const float4*)(src + c8 * 8);
    float4 a = s4[0], bb = s4[1];
    u16 tmp[8] = {f2bf(a.x),  f2bf(a.y),  f2bf(a.z),  f2bf(a.w),
                  f2bf(bb.x), f2bf(bb.y), f2bf(bb.z), f2bf(bb.w)};
    *(uint4*)(Xb + (size_t)row * 512 + c8 * 8) = *(uint4*)tmp;
  } else if (bid < 3264) {
    int r = bid - 3072;
    wtconv_body(W_qkv, WqkvT, 512, 1536, (r % 24) * 64, (r / 24) * 64, t, tile);
  } else {
    int r = bid - 3264;
    wtconv_body(W_out, WoutT, 512, 512, (r % 8) * 64, (r / 8) * 64, t, tile);
  }
}

// ---------------------------------------------------------------------------
// bf16 MFMA GEMM (qkv): C[M,N] = A[M,K] @ Bt[N,K]^T, bf16 out.  128x128 tile.
// qscale: cols<512 (q third) -> (acc + u)*0.125 (u-fold).
// NEW: q is only consumed for x rows (pos>=768), so tiles with bn<512 and
// within-b m-tile < 6 (memory rows) are skipped entirely (192 of 768 blocks,
// 25% of the FLOPs).  Their qkv_bf region is never read downstream.
// ---------------------------------------------------------------------------
__global__ __launch_bounds__(256) void gemm_bf16(
    const u16* __restrict__ A, const u16* __restrict__ Bt,
    int lda, int ldb, int ksteps,
    u16* __restrict__ Cbf, int ldc, int qscale, const float* __restrict__ uq)
{
  __shared__ u16 As[128 * 64];
  __shared__ u16 Bs[128 * 64];
  int tid = threadIdx.x;
  int id = blockIdx.y * gridDim.x + blockIdx.x;
  int gy = gridDim.y;
  int bm = (id % gy) * 128, bn = (id / gy) * 128;
  if (qscale && bn < 512 && ((bm >> 7) & 7) < 6) return;  // mem-row q tile: dead
  int ln = tid & 15, quad = (tid >> 4) & 3, w = tid >> 6;
  int moff = (w >> 1) * 64, noff = (w & 1) * 64;
  int l7 = ln & 7;
  floatx4 acc[4][4];
#pragma unroll
  for (int mi = 0; mi < 4; mi++)
#pragma unroll
    for (int ni = 0; ni < 4; ni++) acc[mi][ni] = (floatx4){0.f, 0.f, 0.f, 0.f};

  int srow[4], sgch[4];
#pragma unroll
  for (int v = 0; v < 4; v++) {
    int f = v * 256 + tid;
    srow[v] = f >> 3;
    sgch[v] = (f & 7) ^ ((f >> 3) & 7);
  }

  for (int ks = 0; ks < ksteps; ks++) {
    int k0 = ks * 64;
#pragma unroll
    for (int v = 0; v < 4; v++) {
      gload_lds16(A + (size_t)(bm + srow[v]) * lda + k0 + sgch[v] * 8,
                  &As[(v * 256 + tid) * 8]);
      gload_lds16(Bt + (size_t)(bn + srow[v]) * ldb + k0 + sgch[v] * 8,
                  &Bs[(v * 256 + tid) * 8]);
    }
    __syncthreads();
#pragma unroll
    for (int kb = 0; kb < 2; kb++) {
      short8 af[4], bfr[4];
#pragma unroll
      for (int mi = 0; mi < 4; mi++) {
        int row = moff + mi * 16 + ln;
        af[mi] = *(const short8*)&As[row * 64 + (((quad + 4 * kb) ^ l7) << 3)];
      }
#pragma unroll
      for (int ni = 0; ni < 4; ni++) {
        int row = noff + ni * 16 + ln;
        bfr[ni] = *(const short8*)&Bs[row * 64 + (((quad + 4 * kb) ^ l7) << 3)];
      }
#pragma unroll
      for (int mi = 0; mi < 4; mi++)
#pragma unroll
        for (int ni = 0; ni < 4; ni++)
          acc[mi][ni] = __builtin_amdgcn_mfma_f32_16x16x32_bf16(
              af[mi], bfr[ni], acc[mi][ni], 0, 0, 0);
    }
    __syncthreads();
  }

  int r0 = bm + moff + quad * 4;
#pragma unroll
  for (int ni = 0; ni < 4; ni++) {
    int col = bn + noff + ni * 16 + ln;
    bool isq = qscale && col < 512;
    float scale = isq ? 0.125f : 1.f;
    float uadd = isq ? uq[col & 63] : 0.f;
#pragma unroll
    for (int mi = 0; mi < 4; mi++) {
#pragma unroll
      for (int r = 0; r < 4; r++) {
        int row = r0 + mi * 16 + r;
        Cbf[(size_t)row * ldc + col] = f2bf((acc[mi][ni][r] + uadd) * scale);
      }
    }
  }
}

// ---------------------------------------------------------------------------
// 64x64-tile bf16 GEMM, fp32 out + bias (output projection).  256 blocks.
// ---------------------------------------------------------------------------
__global__ __launch_bounds__(256) void gemm_bf16_64(
    const u16* __restrict__ A, const u16* __restrict__ Bt,
    int lda, int ldb, int ksteps,
    float* __restrict__ Cf, int ldc, const float* __restrict__ bias)
{
  __shared__ u16 As[64 * 64];
  __shared__ u16 Bs[64 * 64];
  int tid = threadIdx.x;
  int id = blockIdx.y * gridDim.x + blockIdx.x;
  int gy = gridDim.y;
  int bm = (id % gy) * 64, bn = (id / gy) * 64;
  int ln = tid & 15, quad = (tid >> 4) & 3, w = tid >> 6;
  int moff = (w >> 1) * 32, noff = (w & 1) * 32;
  int l7 = ln & 7;
  floatx4 acc[2][2];
#pragma unroll
  for (int mi = 0; mi < 2; mi++)
#pragma unroll
    for (int ni = 0; ni < 2; ni++) acc[mi][ni] = (floatx4){0.f, 0.f, 0.f, 0.f};

  int srow[2], sgch[2];
#pragma unroll
  for (int v = 0; v < 2; v++) {
    int f = v * 256 + tid;
    srow[v] = f >> 3;
    sgch[v] = (f & 7) ^ ((f >> 3) & 7);
  }

  for (int ks = 0; ks < ksteps; ks++) {
    int k0 = ks * 64;
#pragma unroll
    for (int v = 0; v < 2; v++) {
      gload_lds16(A + (size_t)(bm + srow[v]) * lda + k0 + sgch[v] * 8,
                  &As[(v * 256 + tid) * 8]);
      gload_lds16(Bt + (size_t)(bn + srow[v]) * ldb + k0 + sgch[v] * 8,
                  &Bs[(v * 256 + tid) * 8]);
    }
    __syncthreads();
#pragma unroll
    for (int kb = 0; kb < 2; kb++) {
      short8 af[2], bfr[2];
#pragma unroll
      for (int mi = 0; mi < 2; mi++) {
        int row = moff + mi * 16 + ln;
        af[mi] = *(const short8*)&As[row * 64 + (((quad + 4 * kb) ^ l7) << 3)];
      }
#pragma unroll
      for (int ni = 0; ni < 2; ni++) {
        int row = noff + ni * 16 + ln;
        bfr[ni] = *(const short8*)&Bs[row * 64 + (((quad + 4 * kb) ^ l7) << 3)];
      }
#pragma unroll
      for (int mi = 0; mi < 2; mi++)
#pragma unroll
        for (int ni = 0; ni < 2; ni++)
          acc[mi][ni] = __builtin_amdgcn_mfma_f32_16x16x32_bf16(
              af[mi], bfr[ni], acc[mi][ni], 0, 0, 0);
    }
    __syncthreads();
  }

  int r0 = bm + moff + quad * 4;
#pragma unroll
  for (int ni = 0; ni < 2; ni++) {
    int col = bn + noff + ni * 16 + ln;
    float cv = bias[col];
#pragma unroll
    for (int mi = 0; mi < 2; mi++) {
#pragma unroll
      for (int r = 0; r < 4; r++) {
        int row = r0 + mi * 16 + r;
        Cf[(size_t)row * ldc + col] = acc[mi][ni][r] + cv;
      }
    }
  }
}

// ---------------------------------------------------------------------------
// MFMA flash attention v15: split-8 -> split-2.
// R4 post-mortem: no pipe >25% busy; per-block fixed costs (Q load, butterfly
// epilogue, Opart partial write) replicated 8x dominated.  Now 512 blocks
// (b,h,nt,p<2), each owning 8 KV-tiles (mt=p+2t) as 4 software-pipelined
// PAIRS with ping-pong V buffers (Vt[4], 5 barriers):
//   iter g: write V-pair g+1 (regs loaded in g-1) | load V-pair g+2 |
//           load K(u) | T(u),tsh(u) | load R(v) | QK(u),logits(u) |
//           load K(v) | prefetch R(next pair) | T(v),tsh(v) | PV(u) |
//           QK(v),logits(v) | PV(v) | barrier
// Buffer hazards: pair P lives in Vt[2(P&1)..]; overwrite of pair g's buffers
// happens at top of iter g+1 (write pair g+2... wait: pair g+2 shares g's
// buffers, written top of g+1) -- protected by barrier at END of iter g. ✓
// Phantom tiles (mt >= ntiles) are fully masked by the generalized causal
// condition (16ni+l15) > sb+il  => exp(-1e30)=0, exact zero contribution.
// XCD swizle: blockIdx.x = h => all 64 blocks of one head land on one XCD;
// per-XCD working set (K/V panels + Q + Rrel) ~3.5MB fits the 4MB L2.
// Epilogue 1x (was 8x); Opart/combine traffic 4x smaller.
// ---------------------------------------------------------------------------
__global__ __launch_bounds__(256) void attn_mfma(
    const u16* __restrict__ qkv_bf, const u16* __restrict__ Rrel_bf,
    const float* __restrict__ vR,
    u16* __restrict__ Opart, float* __restrict__ lbuf)
{
  constexpr int LD = 72;  // Vt/Ps row stride (144 B)
  __shared__ u16 Vt[4][64 * LD];
  __shared__ u16 Ps[64 * LD];

  int h = blockIdx.x;                       // XCD selector
  int nt = blockIdx.y >> 1, p = blockIdx.y & 1;
  int b = blockIdx.z;
  int n0 = nt * 64, bh = b * 8 + h;
  int tid = threadIdx.x;
  int w = tid >> 6, lane = tid & 63;
  int l15 = lane & 15, quad = lane >> 4, q8 = quad * 8;

  // staging geometry for V
  int sr0 = tid >> 3, sc8 = tid & 7;
  int sr1 = (256 + tid) >> 3;
  int vg0 = ((sr0 >> 3) ^ sc8) * 8 + (sr0 & 7);
  int vg1 = ((sr1 >> 3) ^ sc8) * 8 + (sr1 & 7);

  const u16* kpart = qkv_bf + (size_t)(b * kTOTAL) * 1536 + 512 + h * 64;
  const float* vRh = vR + h * 1024;
  int s_base_w = kMEM + n0 + 16 * w;

  // ---- Q fragments (once per block now, was 8x) ----
  const u16* qrow = qkv_bf + (size_t)(b * kTOTAL + kMEM + n0 + 16 * w + l15) * 1536 + h * 64;
  short8 qf0 = *(const short8*)(qrow + q8);
  short8 qf1 = *(const short8*)(qrow + 32 + q8);

  // ---- bpermute byte-index for the shifted-T diagonal gather ----
  int bidx[4];
#pragma unroll
  for (int r = 0; r < 4; r++) {
    int il = 4 * quad + r;
    bidx[r] = ((quad << 4) | ((il + 15 - l15) & 15)) << 2;
  }

  // ---- load/phase helpers ----
  auto load_V = [&](int mtu, int mtv, uint4 (&vr)[4]) {
    const u16* va = kpart + (size_t)mtu * 64 * 1536 + 512;
    const u16* vb = kpart + (size_t)mtv * 64 * 1536 + 512;
    vr[0] = *(const uint4*)(va + (size_t)sr0 * 1536 + sc8 * 8);
    vr[1] = *(const uint4*)(va + (size_t)sr1 * 1536 + sc8 * 8);
    vr[2] = *(const uint4*)(vb + (size_t)sr0 * 1536 + sc8 * 8);
    vr[3] = *(const uint4*)(vb + (size_t)sr1 * 1536 + sc8 * 8);
  };
  auto write_V = [&](uint4 (&vr)[4], u16* bu, u16* bv) {
    const u16* c0 = (const u16*)&vr[0];
    const u16* c1 = (const u16*)&vr[1];
    const u16* c2 = (const u16*)&vr[2];
    const u16* c3 = (const u16*)&vr[3];
#pragma unroll
    for (int i = 0; i < 8; i++) {
      bu[(sc8 * 8 + i) * LD + vg0] = c0[i];
      bu[(sc8 * 8 + i) * LD + vg1] = c1[i];
      bv[(sc8 * 8 + i) * LD + vg0] = c2[i];
      bv[(sc8 * 8 + i) * LD + vg1] = c3[i];
    }
  };
  auto load_K = [&](int mt, short8 (&k0)[4], short8 (&k1)[4]) {
#pragma unroll
    for (int ni = 0; ni < 4; ni++) {
      const u16* kr = kpart + (size_t)(mt * 64 + 16 * ni + l15) * 1536;
      k0[ni] = *(const short8*)(kr + q8);
      k1[ni] = *(const short8*)(kr + 32 + q8);
    }
  };
  auto load_R = [&](int sb, short8 (&r0)[5], short8 (&r1)[5], float (&vc)[5]) {
#pragma unroll
    for (int ct = 0; ct < 5; ct++) {
      int s = sb - 63 + 16 * ct + l15;
      s = min(max(s, 0), 1023);
      const u16* rr = Rrel_bf + (size_t)s * 512 + h * 64;
      r0[ct] = *(const short8*)(rr + q8);
      r1[ct] = *(const short8*)(rr + 32 + q8);
      vc[ct] = vRh[s];
    }
  };

  floatx4 o_acc[4];
  float l_i[4];
#pragma unroll
  for (int r = 0; r < 4; r++) l_i[r] = 0.f;
#pragma unroll
  for (int nd = 0; nd < 4; nd++) o_acc[nd] = (floatx4){0.f, 0.f, 0.f, 0.f};

  auto do_T = [&](short8 (&rb0)[5], short8 (&rb1)[5], float (&vRc)[5],
                  float (&tf)[5][4]) {
#pragma unroll
    for (int ct = 0; ct < 5; ct++) {
      floatx4 t = (floatx4){0.f, 0.f, 0.f, 0.f};
      t = __builtin_amdgcn_mfma_f32_16x16x32_bf16(qf0, rb0[ct], t, 0, 0, 0);
      t = __builtin_amdgcn_mfma_f32_16x16x32_bf16(qf1, rb1[ct], t, 0, 0, 0);
#pragma unroll
      for (int r = 0; r < 4; r++) tf[ct][r] = t[r] + vRc[ct];
    }
  };
  auto do_tsh = [&](float (&tf)[5][4], float (&tsh)[4][4]) {
#pragma unroll
    for (int ni = 0; ni < 4; ni++) {
#pragma unroll
      for (int r = 0; r < 4; r++) {
        int il = 4 * quad + r;
        float tv = (l15 < il) ? tf[4 - ni][r] : tf[3 - ni][r];
        tsh[ni][r] = __int_as_float(
            __builtin_amdgcn_ds_bpermute(bidx[r], __float_as_int(tv)));
      }
    }
  };
  auto do_QK = [&](short8 (&kb0)[4], short8 (&kb1)[4], floatx4 (&sa)[4]) {
#pragma unroll
    for (int ni = 0; ni < 4; ni++) {
      floatx4 s4 = (floatx4){0.f, 0.f, 0.f, 0.f};
      s4 = __builtin_amdgcn_mfma_f32_16x16x32_bf16(qf0, kb0[ni], s4, 0, 0, 0);
      s4 = __builtin_amdgcn_mfma_f32_16x16x32_bf16(qf1, kb1[ni], s4, 0, 0, 0);
      sa[ni] = s4;
    }
  };
  auto do_logits = [&](floatx4 (&sa)[4], float (&tsh)[4][4], int sb) {
#pragma unroll
    for (int ni = 0; ni < 4; ni++) {
#pragma unroll
      for (int r = 0; r < 4; r++) {
        int il = 4 * quad + r;
        float val = sa[ni][r] + tsh[ni][r];
        if ((16 * ni + l15) > (sb + il)) val = -1e30f;   // causal + phantom mask
        float e = __expf(val);
        l_i[r] += e;
        int prow = 16 * w + il;
        Ps[prow * LD + (l15 & 7) + (((2 * ni + (l15 >> 3)) ^ (prow >> 3)) << 3)] =
            f2bf(e);
      }
    }
  };
  auto do_PV = [&](const u16* VtX) {
    int rowq = 16 * w + l15, rr3q = rowq >> 3;
    short8 pa0 = *(const short8*)&Ps[rowq * LD + ((quad ^ rr3q) << 3)];
    short8 pa1 = *(const short8*)&Ps[rowq * LD + (((quad + 4) ^ rr3q) << 3)];
#pragma unroll
    for (int nd = 0; nd < 4; nd++) {
      int rowv = 16 * nd + l15, rr3v = rowv >> 3;
      short8 vb0 = *(const short8*)&VtX[rowv * LD + ((quad ^ rr3v) << 3)];
      short8 vb1 = *(const short8*)&VtX[rowv * LD + (((quad + 4) ^ rr3v) << 3)];
      o_acc[nd] = __builtin_amdgcn_mfma_f32_16x16x32_bf16(pa0, vb0, o_acc[nd], 0, 0, 0);
      o_acc[nd] = __builtin_amdgcn_mfma_f32_16x16x32_bf16(pa1, vb1, o_acc[nd], 0, 0, 0);
    }
  };

  // ==== prologue ====
  uint4 vsl[2][4];
  short8 rbP0[2][5], rbP1[2][5];
  float vRcP[2][5];
  load_V(p, p + 2, vsl[0]);
  write_V(vsl[0], Vt[0], Vt[1]);            // compiler waits vmcnt for vsl[0]
  load_V(p + 4, p + 6, vsl[1]);
  load_R(s_base_w - 64 * p, rbP0[0], rbP1[0], vRcP[0]);
  __syncthreads();                          // publishes pair0, drains all vmem

  // ==== 4 pipelined pairs (fully unrolled: all indices static) ====
#pragma unroll
  for (int g = 0; g < 4; g++) {
    int mtU = p + 4 * g, mtV = p + 4 * g + 2;
    int sbU = s_base_w - 64 * mtU, sbV = s_base_w - 64 * mtV;

    if (g < 3) write_V(vsl[(g + 1) & 1], Vt[2 * ((g + 1) & 1)], Vt[2 * ((g + 1) & 1) + 1]);
    if (g < 2) load_V(p + 4 * g + 8, p + 4 * g + 10, vsl[g & 1]);

    short8 kbU0[4], kbU1[4];
    load_K(mtU, kbU0, kbU1);                // consumed at QK(u): ~T+tsh cover

    float tfU[5][4], tshU[4][4];
    do_T(rbP0[g & 1], rbP1[g & 1], vRcP[g & 1], tfU);   // R(u) pre-drained
    do_tsh(tfU, tshU);

    short8 rbV0[5], rbV1[5];
    float vRcV[5];
    load_R(sbV, rbV0, rbV1, vRcV);          // consumed at T(v): ~QK+logits cover

    floatx4 saU[4];
    do_QK(kbU0, kbU1, saU);
    do_logits(saU, tshU, sbU);

    short8 kbV0[4], kbV1[4];
    load_K(mtV, kbV0, kbV1);                // consumed at QK(v): ~T(v)+tsh+PV cover
    if (g < 3)
      load_R(s_base_w - 64 * (p + 4 * (g + 1)),
             rbP0[(g + 1) & 1], rbP1[(g + 1) & 1], vRcP[(g + 1) & 1]);

    float tfV[5][4], tshV[4][4];
    do_T(rbV0, rbV1, vRcV, tfV);
    do_tsh(tfV, tshV);

    do_PV(Vt[2 * (g & 1)]);                 // tile u close

    floatx4 saV[4];
    do_QK(kbV0, kbV1, saV);
    do_logits(saV, tshV, sbV);
    do_PV(Vt[2 * (g & 1) + 1]);             // tile v close

    if (g < 3) __syncthreads();             // publishes pair g+1; frees pair g bufs
  }

  // ---- epilogue (once per block now): butterfly l, write O_p + l_p ----
  int pbase = (p * 64 + bh) * 256;
#pragma unroll
  for (int r = 0; r < 4; r++) {
    float l = l_i[r];
#pragma unroll
    for (int off = 1; off < 16; off <<= 1)
      l += __shfl_xor(l, off, 64);
    int n = n0 + 16 * w + 4 * quad + r;
    u16* orow = Opart + ((size_t)(pbase + n) << 6) + l15;
#pragma unroll
    for (int nd = 0; nd < 4; nd++)
      orow[16 * nd] = f2bf(o_acc[nd][r]);
    if (l15 == 0) lbuf[pbase + n] = l;
  }
}

// ---------------------------------------------------------------------------
// Combine the 2 split-m partials: out = Σ_p O_p / Σ_p l_p  (fixed-max).
// ---------------------------------------------------------------------------
__global__ __launch_bounds__(256) void attn_combine(
    const u16* __restrict__ Opart, const float* __restrict__ lbuf,
    u16* __restrict__ aout_bf)
{
  int idx = blockIdx.x * 256 + threadIdx.x;   // 262144
  int bh = idx >> 12, n = (idx >> 4) & 255, d4 = idx & 15;
  int rowi = bh * 256 + n;
  float den = 0.f;
  float num[4] = {0.f, 0.f, 0.f, 0.f};
#pragma unroll
  for (int p = 0; p < 2; p++) {
    den += lbuf[(p << 14) + rowi];
    uint2 raw = *(const uint2*)(Opart + (((size_t)(p << 14) + rowi) << 6) + d4 * 4);
    const u16* us = (const u16*)&raw;
#pragma unroll
    for (int j = 0; j < 4; j++) num[j] += bf2f(us[j]);
  }
  float inv = 1.f / den;
  int b = bh >> 3, h = bh & 7;
  ushort4 o;
  o.x = f2bf(num[0] * inv);
  o.y = f2bf(num[1] * inv);
  o.z = f2bf(num[2] * inv);
  o.w = f2bf(num[3] * inv);
  *(ushort4*)(aout_bf + (size_t)(b * kSEQ + n) * 512 + h * 64 + d4 * 4) = o;
}

// ---------------------------------------------------------------------------
// Host launcher — 5 dispatches.
// ---------------------------------------------------------------------------
extern "C" void kernel_launch(void* const* d_in, const int* in_sizes, int n_in,
                              void* d_out, int out_size, void* d_ws, size_t ws_size,
                              hipStream_t stream) {
  (void)in_sizes; (void)n_in; (void)out_size; (void)ws_size;
  const float* x      = (const float*)d_in[0];
  const float* memory = (const float*)d_in[1];
  const float* W_qkv  = (const float*)d_in[2];
  const float* W_rel  = (const float*)d_in[3];
  const float* W_out  = (const float*)d_in[4];
  const float* b_out  = (const float*)d_in[5];
  const float* u_emb  = (const float*)d_in[6];
  const float* v_emb  = (const float*)d_in[7];
  float* out = (float*)d_out;

  char* ws = (char*)d_ws;
  u16*   qkv_bf  = (u16*)ws;                         ws += (size_t)12582912 * 2;
  u16*   Xcat_bf = (u16*)ws;                         ws += (size_t)4194304 * 2;
  u16*   aout_bf = (u16*)ws;                         ws += (size_t)1048576 * 2;
  u16*   Opart   = (u16*)ws;                         ws += (size_t)2097152 * 2;   // [p<2][bh][n][d]
  float* lbuf    = (float*)ws;                       ws += (size_t)32768 * 4;     // [p<2][bh][n]
  u16*   WqkvT   = (u16*)ws;                         ws += (size_t)786432 * 2;
  u16*   WoutT   = (u16*)ws;                         ws += (size_t)262144 * 2;
  u16*   Rrel_bf = (u16*)ws;                         ws += (size_t)524288 * 2;
  float* vR      = (float*)ws;                       ws += (size_t)8192 * 4;
  // total ≈ 43 MB

  // 1. fused prep: Rrel + vR' (u-compensated), xcat->bf16, W transposes
  prep_kernel<<<3328, 256, 0, stream>>>(
      x, memory, W_qkv, W_out, W_rel, v_emb, u_emb,
      Xcat_bf, WqkvT, WoutT, Rrel_bf, vR);

  // 2. qkv = Xcat @ W_qkv  (M=8192, N=1536, K=512), bf16 out,
  //    q third gets (acc + u)*0.125; mem-row q tiles skipped
  gemm_bf16<<<dim3(12, 64), 256, 0, stream>>>(
      Xcat_bf, WqkvT, 512, 512, 8, qkv_bf, 1536, 1, u_emb);

  // 3. attention: split-2, 8 tiles/block, 4 pipelined pairs, XCD-swizzled grid
  attn_mfma<<<dim3(8, 8, 8), 256, 0, stream>>>(
      qkv_bf, Rrel_bf, vR, Opart, lbuf);

  // 4. combine the 2 split-m partials
  attn_combine<<<1024, 256, 0, stream>>>(Opart, lbuf, aout_bf);

  // 5. out = aout @ W_out + b_out  (M=2048, N=512, K=512), fp32 out, 256 blocks
  gemm_bf16_64<<<dim3(8, 32), 256, 0, stream>>>(
      aout_bf, WoutT, 512, 512, 8, out, 512, b_out);
}

// Round 6
// 150.309 us; speedup vs baseline: 1.0351x; 1.0351x over previous
//
#include <hip/hip_runtime.h>
#include <hip/hip_bf16.h>
#include <math.h>

typedef unsigned short u16;
typedef unsigned int u32;
typedef __attribute__((ext_vector_type(8))) short short8;
typedef __attribute__((ext_vector_type(4))) float floatx4;

// Problem constants
constexpr int kB     = 8;
constexpr int kSEQ   = 256;
constexpr int kMEM   = 768;
constexpr int kTOTAL = 1024;  // MEM+SEQ

__device__ __forceinline__ float bf2f(u16 u) {
  return __uint_as_float(((u32)u) << 16);
}
__device__ __forceinline__ u16 f2bf(float f) {
  __hip_bfloat16 h = __float2bfloat16(f);
  return *reinterpret_cast<u16*>(&h);
}
__device__ __forceinline__ void gload_lds16(const u16* g, u16* l) {
  __builtin_amdgcn_global_load_lds(
      (__attribute__((address_space(1))) const unsigned int*)g,
      (__attribute__((address_space(3))) unsigned int*)l, 16, 0, 0);
}

// ---------------------------------------------------------------------------
// Fused prep (one kernel, disjoint block ranges):
//   blocks [0,1024):    Rrel_bf[s,:] = bf16(PE(s)@W_rel);
//                       vR'[h,s] = 0.125*(v·R_f32 - u·R_bf16)
//   blocks [1024,3072): xcat -> bf16
//   blocks [3072,3264): W_qkv^T -> bf16
//   blocks [3264,3328): W_out^T -> bf16
// ---------------------------------------------------------------------------
__device__ __forceinline__ void wtconv_body(
    const float* __restrict__ W, u16* __restrict__ Wt, int K, int N,
    int n0, int k0, int tid, float (*tile)[65])
{
  int r = tid >> 4, c4 = (tid & 15) * 4;
#pragma unroll
  for (int v = 0; v < 4; v++) {
    float4 w4 = *(const float4*)(W + (size_t)(k0 + v * 16 + r) * N + n0 + c4);
    tile[v * 16 + r][c4 + 0] = w4.x;
    tile[v * 16 + r][c4 + 1] = w4.y;
    tile[v * 16 + r][c4 + 2] = w4.z;
    tile[v * 16 + r][c4 + 3] = w4.w;
  }
  __syncthreads();
#pragma unroll
  for (int v = 0; v < 4; v++) {
    int rn = v * 16 + r;
    ushort4 o;
    o.x = f2bf(tile[c4 + 0][rn]);
    o.y = f2bf(tile[c4 + 1][rn]);
    o.z = f2bf(tile[c4 + 2][rn]);
    o.w = f2bf(tile[c4 + 3][rn]);
    *(ushort4*)(Wt + (size_t)(n0 + rn) * K + k0 + c4) = o;
  }
}

__global__ __launch_bounds__(256) void prep_kernel(
    const float* __restrict__ x, const float* __restrict__ memf,
    const float* __restrict__ W_qkv, const float* __restrict__ W_out,
    const float* __restrict__ W_rel, const float* __restrict__ v_emb,
    const float* __restrict__ u_emb,
    u16* __restrict__ Xb, u16* __restrict__ WqkvT, u16* __restrict__ WoutT,
    u16* __restrict__ Rrel_bf, float* __restrict__ vR)
{
  __shared__ float tile[64][65];
  __shared__ float pe[22];
  __shared__ float prod[512];
  int bid = blockIdx.x;
  int t = threadIdx.x;
  if (bid < 1024) {
    int s = bid;
    if (t < 22) {
      int o = (t < 11) ? t : (t - 11);
      float mult = ldexpf(3.14159265358979323846f, o - 10);  // 2^(o-10) * pi
      float ang = (float)s * mult;
      pe[t] = (t < 11) ? sinf(ang) : cosf(ang);
    }
    __syncthreads();
#pragma unroll
    for (int c = 0; c < 2; c++) {
      int j = t + c * 256;
      float acc = 0.f;
#pragma unroll
      for (int o = 0; o < 22; ++o) acc += pe[o] * W_rel[o * 512 + j];
      u16 rbf = f2bf(acc);
      Rrel_bf[(size_t)s * 512 + j] = rbf;
      prod[j] = acc * v_emb[j & 63] - bf2f(rbf) * u_emb[j & 63];
    }
    __syncthreads();
    if (t < 8) {
      float a = 0.f;
#pragma unroll 8
      for (int d = 0; d < 64; d++) a += prod[t * 64 + d];
      vR[t * 1024 + s] = a * 0.125f;   // prescaled
    }
  } else if (bid < 3072) {
    int idx = (bid - 1024) * 256 + t;        // 8 elems each
    int row = idx >> 6, c8 = idx & 63;
    int b = row >> 10, pos = row & 1023;
    const float* src = (pos < kMEM)
        ? memf + (size_t)(b * kMEM + pos) * 512
        : x    + (size_t)(b * kSEQ + pos - kMEM) * 512;
    const float4* s4 = (const float4*)(src + c8 * 8);
    float4 a = s4[0], bb = s4[1];
    u16 tmp[8] = {f2bf(a.x),  f2bf(a.y),  f2bf(a.z),  f2bf(a.w),
                  f2bf(bb.x), f2bf(bb.y), f2bf(bb.z), f2bf(bb.w)};
    *(uint4*)(Xb + (size_t)row * 512 + c8 * 8) = *(uint4*)tmp;
  } else if (bid < 3264) {
    int r = bid - 3072;
    wtconv_body(W_qkv, WqkvT, 512, 1536, (r % 24) * 64, (r / 24) * 64, t, tile);
  } else {
    int r = bid - 3264;
    wtconv_body(W_out, WoutT, 512, 512, (r % 8) * 64, (r / 8) * 64, t, tile);
  }
}

// ---------------------------------------------------------------------------
// bf16 MFMA GEMM (qkv): C[M,N] = A[M,K] @ Bt[N,K]^T, bf16 out.  128x128 tile.
// qscale: cols<512 (q third) -> (acc + u)*0.125 (u-fold).
// Mem-row q tiles (never read downstream) skipped: 25% of the FLOPs.
// ---------------------------------------------------------------------------
__global__ __launch_bounds__(256) void gemm_bf16(
    const u16* __restrict__ A, const u16* __restrict__ Bt,
    int lda, int ldb, int ksteps,
    u16* __restrict__ Cbf, int ldc, int qscale, const float* __restrict__ uq)
{
  __shared__ u16 As[128 * 64];
  __shared__ u16 Bs[128 * 64];
  int tid = threadIdx.x;
  int id = blockIdx.y * gridDim.x + blockIdx.x;
  int gy = gridDim.y;
  int bm = (id % gy) * 128, bn = (id / gy) * 128;
  if (qscale && bn < 512 && ((bm >> 7) & 7) < 6) return;  // mem-row q tile: dead
  int ln = tid & 15, quad = (tid >> 4) & 3, w = tid >> 6;
  int moff = (w >> 1) * 64, noff = (w & 1) * 64;
  int l7 = ln & 7;
  floatx4 acc[4][4];
#pragma unroll
  for (int mi = 0; mi < 4; mi++)
#pragma unroll
    for (int ni = 0; ni < 4; ni++) acc[mi][ni] = (floatx4){0.f, 0.f, 0.f, 0.f};

  int srow[4], sgch[4];
#pragma unroll
  for (int v = 0; v < 4; v++) {
    int f = v * 256 + tid;
    srow[v] = f >> 3;
    sgch[v] = (f & 7) ^ ((f >> 3) & 7);
  }

  for (int ks = 0; ks < ksteps; ks++) {
    int k0 = ks * 64;
#pragma unroll
    for (int v = 0; v < 4; v++) {
      gload_lds16(A + (size_t)(bm + srow[v]) * lda + k0 + sgch[v] * 8,
                  &As[(v * 256 + tid) * 8]);
      gload_lds16(Bt + (size_t)(bn + srow[v]) * ldb + k0 + sgch[v] * 8,
                  &Bs[(v * 256 + tid) * 8]);
    }
    __syncthreads();
#pragma unroll
    for (int kb = 0; kb < 2; kb++) {
      short8 af[4], bfr[4];
#pragma unroll
      for (int mi = 0; mi < 4; mi++) {
        int row = moff + mi * 16 + ln;
        af[mi] = *(const short8*)&As[row * 64 + (((quad + 4 * kb) ^ l7) << 3)];
      }
#pragma unroll
      for (int ni = 0; ni < 4; ni++) {
        int row = noff + ni * 16 + ln;
        bfr[ni] = *(const short8*)&Bs[row * 64 + (((quad + 4 * kb) ^ l7) << 3)];
      }
#pragma unroll
      for (int mi = 0; mi < 4; mi++)
#pragma unroll
        for (int ni = 0; ni < 4; ni++)
          acc[mi][ni] = __builtin_amdgcn_mfma_f32_16x16x32_bf16(
              af[mi], bfr[ni], acc[mi][ni], 0, 0, 0);
    }
    __syncthreads();
  }

  int r0 = bm + moff + quad * 4;
#pragma unroll
  for (int ni = 0; ni < 4; ni++) {
    int col = bn + noff + ni * 16 + ln;
    bool isq = qscale && col < 512;
    float scale = isq ? 0.125f : 1.f;
    float uadd = isq ? uq[col & 63] : 0.f;
#pragma unroll
    for (int mi = 0; mi < 4; mi++) {
#pragma unroll
      for (int r = 0; r < 4; r++) {
        int row = r0 + mi * 16 + r;
        Cbf[(size_t)row * ldc + col] = f2bf((acc[mi][ni][r] + uadd) * scale);
      }
    }
  }
}

// ---------------------------------------------------------------------------
// 64x64-tile bf16 GEMM, fp32 out + bias (output projection).  256 blocks.
// ---------------------------------------------------------------------------
__global__ __launch_bounds__(256) void gemm_bf16_64(
    const u16* __restrict__ A, const u16* __restrict__ Bt,
    int lda, int ldb, int ksteps,
    float* __restrict__ Cf, int ldc, const float* __restrict__ bias)
{
  __shared__ u16 As[64 * 64];
  __shared__ u16 Bs[64 * 64];
  int tid = threadIdx.x;
  int id = blockIdx.y * gridDim.x + blockIdx.x;
  int gy = gridDim.y;
  int bm = (id % gy) * 64, bn = (id / gy) * 64;
  int ln = tid & 15, quad = (tid >> 4) & 3, w = tid >> 6;
  int moff = (w >> 1) * 32, noff = (w & 1) * 32;
  int l7 = ln & 7;
  floatx4 acc[2][2];
#pragma unroll
  for (int mi = 0; mi < 2; mi++)
#pragma unroll
    for (int ni = 0; ni < 2; ni++) acc[mi][ni] = (floatx4){0.f, 0.f, 0.f, 0.f};

  int srow[2], sgch[2];
#pragma unroll
  for (int v = 0; v < 2; v++) {
    int f = v * 256 + tid;
    srow[v] = f >> 3;
    sgch[v] = (f & 7) ^ ((f >> 3) & 7);
  }

  for (int ks = 0; ks < ksteps; ks++) {
    int k0 = ks * 64;
#pragma unroll
    for (int v = 0; v < 2; v++) {
      gload_lds16(A + (size_t)(bm + srow[v]) * lda + k0 + sgch[v] * 8,
                  &As[(v * 256 + tid) * 8]);
      gload_lds16(Bt + (size_t)(bn + srow[v]) * ldb + k0 + sgch[v] * 8,
                  &Bs[(v * 256 + tid) * 8]);
    }
    __syncthreads();
#pragma unroll
    for (int kb = 0; kb < 2; kb++) {
      short8 af[2], bfr[2];
#pragma unroll
      for (int mi = 0; mi < 2; mi++) {
        int row = moff + mi * 16 + ln;
        af[mi] = *(const short8*)&As[row * 64 + (((quad + 4 * kb) ^ l7) << 3)];
      }
#pragma unroll
      for (int ni = 0; ni < 2; ni++) {
        int row = noff + ni * 16 + ln;
        bfr[ni] = *(const short8*)&Bs[row * 64 + (((quad + 4 * kb) ^ l7) << 3)];
      }
#pragma unroll
      for (int mi = 0; mi < 2; mi++)
#pragma unroll
        for (int ni = 0; ni < 2; ni++)
          acc[mi][ni] = __builtin_amdgcn_mfma_f32_16x16x32_bf16(
              af[mi], bfr[ni], acc[mi][ni], 0, 0, 0);
    }
    __syncthreads();
  }

  int r0 = bm + moff + quad * 4;
#pragma unroll
  for (int ni = 0; ni < 2; ni++) {
    int col = bn + noff + ni * 16 + ln;
    float cv = bias[col];
#pragma unroll
    for (int mi = 0; mi < 2; mi++) {
#pragma unroll
      for (int r = 0; r < 4; r++) {
        int row = r0 + mi * 16 + r;
        Cf[(size_t)row * ldc + col] = acc[mi][ni][r] + cv;
      }
    }
  }
}

// ---------------------------------------------------------------------------
// MFMA flash attention v16: split-4 (the v14/v15 interpolation).
// R5 post-mortem: split-2 halved traffic (FETCH 9.9MB ✓) but dropped resident
// waves (occupancy 25->10%) -- the kernel is latency-bound, so concurrency,
// not traffic, is the binding resource.  v16: 1024 blocks (4/CU), 4 tiles per
// block as 2 pipelined pairs, LDS back to Vt[2]+Ps = 27648 (5 blocks/CU) by
// reusing the V ping-pong across pairs:
//   prologue: V(pair0)->LDS; V(pair1)->regs; R(U0); barrier
//   iter0: K(U) | T/tsh(U) | R(V) | QK/logits(U) | K(V) | R(nextU) |
//          T/tsh(V) | PV(u=Vt0) | QK/logits(V) | PV(v=Vt1) | barrier
//   iter1: write_V(pair1->Vt0,Vt1) | same body | pre-PV barrier | PVs
// 3 barriers.  Tiles mt = {p, p+4, p+8, p+12}, phantoms exactly masked by
// (16ni+l15) > sb+il.  blockIdx.x = h keeps one head per XCD (L2-resident
// K/V/R working set, proven by R5's FETCH drop).
// ---------------------------------------------------------------------------
__global__ __launch_bounds__(256) void attn_mfma(
    const u16* __restrict__ qkv_bf, const u16* __restrict__ Rrel_bf,
    const float* __restrict__ vR,
    u16* __restrict__ Opart, float* __restrict__ lbuf)
{
  constexpr int LD = 72;  // Vt/Ps row stride (144 B)
  __shared__ u16 Vt[2][64 * LD];
  __shared__ u16 Ps[64 * LD];

  int h = blockIdx.x;                       // XCD selector
  int nt = blockIdx.y >> 2, p = blockIdx.y & 3;
  int b = blockIdx.z;
  int n0 = nt * 64, bh = b * 8 + h;
  int tid = threadIdx.x;
  int w = tid >> 6, lane = tid & 63;
  int l15 = lane & 15, quad = lane >> 4, q8 = quad * 8;

  // staging geometry for V
  int sr0 = tid >> 3, sc8 = tid & 7;
  int sr1 = (256 + tid) >> 3;
  int vg0 = ((sr0 >> 3) ^ sc8) * 8 + (sr0 & 7);
  int vg1 = ((sr1 >> 3) ^ sc8) * 8 + (sr1 & 7);

  const u16* kpart = qkv_bf + (size_t)(b * kTOTAL) * 1536 + 512 + h * 64;
  const float* vRh = vR + h * 1024;
  int s_base_w = kMEM + n0 + 16 * w;

  // ---- Q fragments (once per block) ----
  const u16* qrow = qkv_bf + (size_t)(b * kTOTAL + kMEM + n0 + 16 * w + l15) * 1536 + h * 64;
  short8 qf0 = *(const short8*)(qrow + q8);
  short8 qf1 = *(const short8*)(qrow + 32 + q8);

  // ---- bpermute byte-index for the shifted-T diagonal gather ----
  int bidx[4];
#pragma unroll
  for (int r = 0; r < 4; r++) {
    int il = 4 * quad + r;
    bidx[r] = ((quad << 4) | ((il + 15 - l15) & 15)) << 2;
  }

  // ---- load/phase helpers ----
  auto load_V = [&](int mtu, int mtv, uint4 (&vr)[4]) {
    const u16* va = kpart + (size_t)mtu * 64 * 1536 + 512;
    const u16* vb = kpart + (size_t)mtv * 64 * 1536 + 512;
    vr[0] = *(const uint4*)(va + (size_t)sr0 * 1536 + sc8 * 8);
    vr[1] = *(const uint4*)(va + (size_t)sr1 * 1536 + sc8 * 8);
    vr[2] = *(const uint4*)(vb + (size_t)sr0 * 1536 + sc8 * 8);
    vr[3] = *(const uint4*)(vb + (size_t)sr1 * 1536 + sc8 * 8);
  };
  auto write_V = [&](uint4 (&vr)[4], u16* bu, u16* bv) {
    const u16* c0 = (const u16*)&vr[0];
    const u16* c1 = (const u16*)&vr[1];
    const u16* c2 = (const u16*)&vr[2];
    const u16* c3 = (const u16*)&vr[3];
#pragma unroll
    for (int i = 0; i < 8; i++) {
      bu[(sc8 * 8 + i) * LD + vg0] = c0[i];
      bu[(sc8 * 8 + i) * LD + vg1] = c1[i];
      bv[(sc8 * 8 + i) * LD + vg0] = c2[i];
      bv[(sc8 * 8 + i) * LD + vg1] = c3[i];
    }
  };
  auto load_K = [&](int mt, short8 (&k0)[4], short8 (&k1)[4]) {
#pragma unroll
    for (int ni = 0; ni < 4; ni++) {
      const u16* kr = kpart + (size_t)(mt * 64 + 16 * ni + l15) * 1536;
      k0[ni] = *(const short8*)(kr + q8);
      k1[ni] = *(const short8*)(kr + 32 + q8);
    }
  };
  auto load_R = [&](int sb, short8 (&r0)[5], short8 (&r1)[5], float (&vc)[5]) {
#pragma unroll
    for (int ct = 0; ct < 5; ct++) {
      int s = sb - 63 + 16 * ct + l15;
      s = min(max(s, 0), 1023);
      const u16* rr = Rrel_bf + (size_t)s * 512 + h * 64;
      r0[ct] = *(const short8*)(rr + q8);
      r1[ct] = *(const short8*)(rr + 32 + q8);
      vc[ct] = vRh[s];
    }
  };

  floatx4 o_acc[4];
  float l_i[4];
#pragma unroll
  for (int r = 0; r < 4; r++) l_i[r] = 0.f;
#pragma unroll
  for (int nd = 0; nd < 4; nd++) o_acc[nd] = (floatx4){0.f, 0.f, 0.f, 0.f};

  auto do_T = [&](short8 (&rb0)[5], short8 (&rb1)[5], float (&vRc)[5],
                  float (&tf)[5][4]) {
#pragma unroll
    for (int ct = 0; ct < 5; ct++) {
      floatx4 t = (floatx4){0.f, 0.f, 0.f, 0.f};
      t = __builtin_amdgcn_mfma_f32_16x16x32_bf16(qf0, rb0[ct], t, 0, 0, 0);
      t = __builtin_amdgcn_mfma_f32_16x16x32_bf16(qf1, rb1[ct], t, 0, 0, 0);
#pragma unroll
      for (int r = 0; r < 4; r++) tf[ct][r] = t[r] + vRc[ct];
    }
  };
  auto do_tsh = [&](float (&tf)[5][4], float (&tsh)[4][4]) {
#pragma unroll
    for (int ni = 0; ni < 4; ni++) {
#pragma unroll
      for (int r = 0; r < 4; r++) {
        int il = 4 * quad + r;
        float tv = (l15 < il) ? tf[4 - ni][r] : tf[3 - ni][r];
        tsh[ni][r] = __int_as_float(
            __builtin_amdgcn_ds_bpermute(bidx[r], __float_as_int(tv)));
      }
    }
  };
  auto do_QK = [&](short8 (&kb0)[4], short8 (&kb1)[4], floatx4 (&sa)[4]) {
#pragma unroll
    for (int ni = 0; ni < 4; ni++) {
      floatx4 s4 = (floatx4){0.f, 0.f, 0.f, 0.f};
      s4 = __builtin_amdgcn_mfma_f32_16x16x32_bf16(qf0, kb0[ni], s4, 0, 0, 0);
      s4 = __builtin_amdgcn_mfma_f32_16x16x32_bf16(qf1, kb1[ni], s4, 0, 0, 0);
      sa[ni] = s4;
    }
  };
  auto do_logits = [&](floatx4 (&sa)[4], float (&tsh)[4][4], int sb) {
#pragma unroll
    for (int ni = 0; ni < 4; ni++) {
#pragma unroll
      for (int r = 0; r < 4; r++) {
        int il = 4 * quad + r;
        float val = sa[ni][r] + tsh[ni][r];
        if ((16 * ni + l15) > (sb + il)) val = -1e30f;   // causal + phantom mask
        float e = __expf(val);
        l_i[r] += e;
        int prow = 16 * w + il;
        Ps[prow * LD + (l15 & 7) + (((2 * ni + (l15 >> 3)) ^ (prow >> 3)) << 3)] =
            f2bf(e);
      }
    }
  };
  auto do_PV = [&](const u16* VtX) {
    int rowq = 16 * w + l15, rr3q = rowq >> 3;
    short8 pa0 = *(const short8*)&Ps[rowq * LD + ((quad ^ rr3q) << 3)];
    short8 pa1 = *(const short8*)&Ps[rowq * LD + (((quad + 4) ^ rr3q) << 3)];
#pragma unroll
    for (int nd = 0; nd < 4; nd++) {
      int rowv = 16 * nd + l15, rr3v = rowv >> 3;
      short8 vb0 = *(const short8*)&VtX[rowv * LD + ((quad ^ rr3v) << 3)];
      short8 vb1 = *(const short8*)&VtX[rowv * LD + (((quad + 4) ^ rr3v) << 3)];
      o_acc[nd] = __builtin_amdgcn_mfma_f32_16x16x32_bf16(pa0, vb0, o_acc[nd], 0, 0, 0);
      o_acc[nd] = __builtin_amdgcn_mfma_f32_16x16x32_bf16(pa1, vb1, o_acc[nd], 0, 0, 0);
    }
  };

  // ==== prologue ====
  short8 rbU0[5], rbU1[5];
  float vRcU[5];
  uint4 vsl[4];                              // pair1 V, reg-held through iter0
  {
    uint4 v0[4];
    load_V(p, p + 4, v0);
    write_V(v0, Vt[0], Vt[1]);               // compiler waits vmcnt for v0
  }
  load_V(p + 8, p + 12, vsl);
  load_R(s_base_w - 64 * p, rbU0, rbU1, vRcU);
  __syncthreads();                           // publishes pair0; drains all vmem

  // ==== 2 pipelined pairs (fully unrolled: all indices static) ====
#pragma unroll
  for (int g = 0; g < 2; g++) {
    int mtU = p + 8 * g, mtV = mtU + 4;
    int sbU = s_base_w - 64 * mtU, sbV = s_base_w - 64 * mtV;

    if (g == 1) write_V(vsl, Vt[0], Vt[1]);  // after end-of-iter0 barrier

    short8 kbU0[4], kbU1[4];
    load_K(mtU, kbU0, kbU1);                 // consumed at QK(u): T+tsh cover

    float tfU[5][4], tshU[4][4];
    do_T(rbU0, rbU1, vRcU, tfU);             // R(u) pre-drained
    do_tsh(tfU, tshU);

    short8 rbV0[5], rbV1[5];
    float vRcV[5];
    load_R(sbV, rbV0, rbV1, vRcV);           // consumed at T(v): QK+logits cover

    floatx4 saU[4];
    do_QK(kbU0, kbU1, saU);
    do_logits(saU, tshU, sbU);

    short8 kbV0[4], kbV1[4];
    load_K(mtV, kbV0, kbV1);                 // consumed at QK(v)
    if (g == 0)
      load_R(s_base_w - 64 * (p + 8), rbU0, rbU1, vRcU);   // next pair's U

    float tfV[5][4], tshV[4][4];
    do_T(rbV0, rbV1, vRcV, tfV);
    do_tsh(tfV, tshV);

    if (g == 1) __syncthreads();             // publish pair1 V before its PV
    do_PV(Vt[0]);                            // tile u close

    floatx4 saV[4];
    do_QK(kbV0, kbV1, saV);
    do_logits(saV, tshV, sbV);
    do_PV(Vt[1]);                            // tile v close

    if (g == 0) __syncthreads();             // frees Vt[0,1] for pair1 write
  }

  // ---- epilogue (once per block): butterfly l, write O_p + l_p ----
  int pbase = (p * 64 + bh) * 256;
#pragma unroll
  for (int r = 0; r < 4; r++) {
    float l = l_i[r];
#pragma unroll
    for (int off = 1; off < 16; off <<= 1)
      l += __shfl_xor(l, off, 64);
    int n = n0 + 16 * w + 4 * quad + r;
    u16* orow = Opart + ((size_t)(pbase + n) << 6) + l15;
#pragma unroll
    for (int nd = 0; nd < 4; nd++)
      orow[16 * nd] = f2bf(o_acc[nd][r]);
    if (l15 == 0) lbuf[pbase + n] = l;
  }
}

// ---------------------------------------------------------------------------
// Combine the 4 split-m partials: out = Σ_p O_p / Σ_p l_p  (fixed-max).
// ---------------------------------------------------------------------------
__global__ __launch_bounds__(256) void attn_combine(
    const u16* __restrict__ Opart, const float* __restrict__ lbuf,
    u16* __restrict__ aout_bf)
{
  int idx = blockIdx.x * 256 + threadIdx.x;   // 262144
  int bh = idx >> 12, n = (idx >> 4) & 255, d4 = idx & 15;
  int rowi = bh * 256 + n;
  float den = 0.f;
  float num[4] = {0.f, 0.f, 0.f, 0.f};
#pragma unroll
  for (int p = 0; p < 4; p++) {
    den += lbuf[(p << 14) + rowi];
    uint2 raw = *(const uint2*)(Opart + (((size_t)(p << 14) + rowi) << 6) + d4 * 4);
    const u16* us = (const u16*)&raw;
#pragma unroll
    for (int j = 0; j < 4; j++) num[j] += bf2f(us[j]);
  }
  float inv = 1.f / den;
  int b = bh >> 3, h = bh & 7;
  ushort4 o;
  o.x = f2bf(num[0] * inv);
  o.y = f2bf(num[1] * inv);
  o.z = f2bf(num[2] * inv);
  o.w = f2bf(num[3] * inv);
  *(ushort4*)(aout_bf + (size_t)(b * kSEQ + n) * 512 + h * 64 + d4 * 4) = o;
}

// ---------------------------------------------------------------------------
// Host launcher — 5 dispatches.
// ---------------------------------------------------------------------------
extern "C" void kernel_launch(void* const* d_in, const int* in_sizes, int n_in,
                              void* d_out, int out_size, void* d_ws, size_t ws_size,
                              hipStream_t stream) {
  (void)in_sizes; (void)n_in; (void)out_size; (void)ws_size;
  const float* x      = (const float*)d_in[0];
  const float* memory = (const float*)d_in[1];
  const float* W_qkv  = (const float*)d_in[2];
  const float* W_rel  = (const float*)d_in[3];
  const float* W_out  = (const float*)d_in[4];
  const float* b_out  = (const float*)d_in[5];
  const float* u_emb  = (const float*)d_in[6];
  const float* v_emb  = (const float*)d_in[7];
  float* out = (float*)d_out;

  char* ws = (char*)d_ws;
  u16*   qkv_bf  = (u16*)ws;                         ws += (size_t)12582912 * 2;
  u16*   Xcat_bf = (u16*)ws;                         ws += (size_t)4194304 * 2;
  u16*   aout_bf = (u16*)ws;                         ws += (size_t)1048576 * 2;
  u16*   Opart   = (u16*)ws;                         ws += (size_t)4194304 * 2;   // [p<4][bh][n][d]
  float* lbuf    = (float*)ws;                       ws += (size_t)65536 * 4;     // [p<4][bh][n]
  u16*   WqkvT   = (u16*)ws;                         ws += (size_t)786432 * 2;
  u16*   WoutT   = (u16*)ws;                         ws += (size_t)262144 * 2;
  u16*   Rrel_bf = (u16*)ws;                         ws += (size_t)524288 * 2;
  float* vR      = (float*)ws;                       ws += (size_t)8192 * 4;
  // total ≈ 47 MB

  // 1. fused prep: Rrel + vR' (u-compensated), xcat->bf16, W transposes
  prep_kernel<<<3328, 256, 0, stream>>>(
      x, memory, W_qkv, W_out, W_rel, v_emb, u_emb,
      Xcat_bf, WqkvT, WoutT, Rrel_bf, vR);

  // 2. qkv = Xcat @ W_qkv  (M=8192, N=1536, K=512), bf16 out,
  //    q third gets (acc + u)*0.125; mem-row q tiles skipped
  gemm_bf16<<<dim3(12, 64), 256, 0, stream>>>(
      Xcat_bf, WqkvT, 512, 512, 8, qkv_bf, 1536, 1, u_emb);

  // 3. attention: split-4, 4 tiles/block, 2 pipelined pairs, XCD-swizzled grid
  attn_mfma<<<dim3(8, 16, 8), 256, 0, stream>>>(
      qkv_bf, Rrel_bf, vR, Opart, lbuf);

  // 4. combine the 4 split-m partials
  attn_combine<<<1024, 256, 0, stream>>>(Opart, lbuf, aout_bf);

  // 5. out = aout @ W_out + b_out  (M=2048, N=512, K=512), fp32 out, 256 blocks
  gemm_bf16_64<<<dim3(8, 32), 256, 0, stream>>>(
      aout_bf, WoutT, 512, 512, 8, out, 512, b_out);
}